// Round 9
// baseline (982.177 us; speedup 1.0000x reference)
//
#include <hip/hip_runtime.h>
#include <hip/hip_bf16.h>
#include <stdint.h>

#define S_ 2048
#define D_ 1024
#define B_ 8
#define KEXP 3072            // 3 * D : [h,l,h] x [h,h,l] fp16 expansion
#define NEGC 1e9f

typedef _Float16 f16;
typedef _Float16 f16x8 __attribute__((ext_vector_type(8)));
typedef float f32x4 __attribute__((ext_vector_type(4)));

#define DSR(dst, addr, off) \
  asm volatile("ds_read_b128 %0, %1 offset:%c2" : "=v"(dst) : "v"(addr), "i"(off))
#define WAITL(n) do { asm volatile("s_waitcnt lgkmcnt(%c0)" :: "i"(n) : "memory"); \
                      __builtin_amdgcn_sched_barrier(0); } while (0)
#define VMC(n) asm volatile("s_waitcnt vmcnt(%c0)" :: "i"(n) : "memory")
#define BAR() __builtin_amdgcn_s_barrier()

// ---------------------------------------------------------------------------
// K0: split fp32 -> fp16 hi/lo 3-term expansion, input pre-scaled by 64.
// pattern A (q): [h,l,h]   pattern B (k): [h,h,l];  blockIdx.y: 0=q, 1=k.
// ---------------------------------------------------------------------------
__global__ __launch_bounds__(256) void split_expand2(const float* __restrict__ qin,
                                                     const float* __restrict__ kin,
                                                     f16* __restrict__ qx,
                                                     f16* __restrict__ kx) {
  const int isB = blockIdx.y;
  const float* in = isB ? kin : qin;
  f16* out = isB ? kx : qx;
  size_t idx = (size_t)blockIdx.x * 256 + threadIdx.x;
  const float4* ip = (const float4*)(in + idx * 8);
  float4 a = ip[0], b = ip[1];
  float vv[8] = {a.x, a.y, a.z, a.w, b.x, b.y, b.z, b.w};
  union { f16 h[24]; uint4 u[3]; } o;
#pragma unroll
  for (int t = 0; t < 8; ++t) {
    float v = vv[t] * 64.0f;
    f16 h = (f16)v;
    float r = v - (float)h;      // exact (Sterbenz)
    f16 l = (f16)r;
    o.h[3 * t + 0] = h;
    o.h[3 * t + 1] = isB ? h : l;
    o.h[3 * t + 2] = isB ? l : h;
  }
  uint4* op = (uint4*)(out + idx * 24);
  op[0] = o.u[0]; op[1] = o.u[1]; op[2] = o.u[2];
}

// ---------------------------------------------------------------------------
// K0c: khT[b][d][j] = fp16(k[b][j][d])
// ---------------------------------------------------------------------------
__global__ __launch_bounds__(256) void transpose_cast(const float* __restrict__ k,
                                                      f16* __restrict__ khT) {
  __shared__ f16 tile[64][65];
  int j0 = blockIdx.x * 64, d0 = blockIdx.y * 64;
  size_t bz = blockIdx.z;
  const float* kb = k + bz * (size_t)S_ * D_;
  f16* ob = khT + bz * (size_t)D_ * S_;
#pragma unroll
  for (int i = 0; i < 16; ++i) {
    int e = threadIdx.x + i * 256;
    int r = e >> 6, c = e & 63;
    tile[c][r] = (f16)kb[(size_t)(j0 + r) * D_ + d0 + c];
  }
  __syncthreads();
#pragma unroll
  for (int i = 0; i < 16; ++i) {
    int e = threadIdx.x + i * 256;
    int r = e >> 6, c = e & 63;
    ob[(size_t)(d0 + r) * S_ + j0 + c] = tile[r][c];
  }
}

// ---------------------------------------------------------------------------
// 8-phase GEMM (B-transposed), snake-order fragment reuse; two schedules:
// PIPE=0: per phase {ds_read -> BAR -> lgkm(0) -> MFMA -> BAR};
//   launch_bounds(512,2), VGPR ~120. Serialized: MfmaUtil ~43% (model:
//   155cy MFMA / (224cy LDS + 155) = 41%).
// PIPE=1: phase p issues p+1's ds_reads (reg sets afX/afY, bfP/bfQ; bfQ held
//   p4->p8), counted lgkmcnt so LDS runs UNDER the MFMA cluster. Ceiling =
//   LDS-bound ~69%. launch_bounds(512,1) => 256-VGPR cap; NFQ=2 live set
//   ~250 fits (R7 spilled only because the (512,2) 128-cap). Grid is 1
//   block/CU anyway (128KB LDS) so no occupancy loss.
// Both: dbuf-2 LDS, stage ledger verified, per-element k-order identical ->
// bit-identical results (absmax must stay exactly 0.03125 — race canary).
// ---------------------------------------------------------------------------
template <int KA, int NN, int BN, int PIPE>
__global__ __launch_bounds__(512, PIPE ? 1 : 2) void gemm8p(const f16* __restrict__ A,
                                                            const f16* __restrict__ Bm,
                                                            float* __restrict__ C,
                                                            const float* scale_ptr,
                                                            float factor) {
  constexpr int NFQ = BN / 128;     // B frags per phase (2 or 1)
  constexpr int GB = NFQ;           // gloads per stgB
  constexpr int NB = 2 * NFQ;       // ds_reads per B-issue
  constexpr int VP3 = 2 + GB;       // vmcnt at p3-end (PIPE)
  constexpr int VP7 = 2 + 2 * GB;   // vmcnt at p7-end (PIPE)
  constexpr int VPR = 4 + 2 * GB;   // prologue vmcnt (PIPE)
  constexpr int NI = KA / 128;      // iterations (2 K-tiles each)
  __shared__ f16 AS[2][256 * 64];   // 2 x 32KB
  __shared__ f16 BS[2][BN * 64];    // 2 x (32|16)KB

  const int tid = threadIdx.x;
  const int lane = tid & 63, wave = tid >> 6;
  const int wm = wave >> 2, wn = wave & 3;        // 2 x 4 wave grid
  const int fr = lane & 15, kq = lane >> 4;

  // XCD-chunk swizzle (bijective: grid multiple of 8)
  int lin = blockIdx.x + gridDim.x * blockIdx.y;
  int ntot = gridDim.x * gridDim.y;
  int nid = (lin & 7) * (ntot >> 3) + (lin >> 3);
  int bz = nid >> 6, rem = nid & 63;
  int bx = rem & 7, by = rem >> 3;

  const f16* Ab = A + (size_t)bz * S_ * KA + (size_t)bx * 256 * KA;
  const f16* Bb = Bm + (size_t)bz * NN * KA + (size_t)by * BN * KA;

  // fragment read bases; XOR swizzle on 16B chunks (0 conflicts, R3-R8)
  const int T0 = fr * 128 + (((0 + kq) ^ (fr & 7)) << 4);
  const int T1 = fr * 128 + (((4 + kq) ^ (fr & 7)) << 4);
  uint32_t asbase = (uint32_t)(uintptr_t)(__attribute__((address_space(3))) f16*)&AS[0][0];
  uint32_t bsbase = (uint32_t)(uintptr_t)(__attribute__((address_space(3))) f16*)&BS[0][0];
  uint32_t aA[2][2], aB[2][2];
#pragma unroll
  for (int b = 0; b < 2; ++b) {
    aA[b][0] = asbase + b * 32768 + wm * 8192 + T0;
    aA[b][1] = asbase + b * 32768 + wm * 8192 + T1;
    aB[b][0] = bsbase + b * (BN * 128) + wn * (BN * 16) + T0;
    aB[b][1] = bsbase + b * (BN * 128) + wn * (BN * 16) + T1;
  }

  // staging: linear LDS dest, inverse-swizzled global source
  const int srl = tid >> 3;
  const int sgc = ((((tid * 16) & 127) ^ (((tid >> 3) & 7) << 4)) >> 1);

  auto stgA = [&](int buf, int unit, int kt) {
#pragma unroll
    for (int i = 0; i < 2; ++i) {
      const f16* src = Ab + (size_t)(unit * 128 + i * 64 + srl) * KA + kt * 64 + sgc;
      __builtin_amdgcn_global_load_lds(
          (const __attribute__((address_space(1))) void*)src,
          (__attribute__((address_space(3))) void*)&AS[buf][unit * 8192 + i * 4096 + wave * 512],
          16, 0, 0);
    }
  };
  auto stgB = [&](int buf, int unit, int kt) {
#pragma unroll
    for (int i = 0; i < GB; ++i) {
      const f16* src = Bb + (size_t)(unit * (BN / 2) + i * 64 + srl) * KA + kt * 64 + sgc;
      __builtin_amdgcn_global_load_lds(
          (const __attribute__((address_space(1))) void*)src,
          (__attribute__((address_space(3))) void*)&BS[buf][unit * (BN * 32) + i * 4096 + wave * 512],
          16, 0, 0);
    }
  };

  f32x4 acc[2][2][4][2];
#pragma unroll
  for (int mh = 0; mh < 2; ++mh)
#pragma unroll
    for (int nh = 0; nh < 2; ++nh)
#pragma unroll
      for (int m = 0; m < 4; ++m)
#pragma unroll
        for (int n = 0; n < NFQ; ++n)
#pragma unroll
          for (int r = 0; r < 4; ++r) acc[mh][nh][m][n][r] = 0.0f;

#define ISS_A(DST, UB, MH) do {                  \
    DSR(DST[0], aA[UB][0], (MH)*16384 + 0);      \
    DSR(DST[1], aA[UB][0], (MH)*16384 + 2048);   \
    DSR(DST[2], aA[UB][0], (MH)*16384 + 4096);   \
    DSR(DST[3], aA[UB][0], (MH)*16384 + 6144);   \
    DSR(DST[4], aA[UB][1], (MH)*16384 + 0);      \
    DSR(DST[5], aA[UB][1], (MH)*16384 + 2048);   \
    DSR(DST[6], aA[UB][1], (MH)*16384 + 4096);   \
    DSR(DST[7], aA[UB][1], (MH)*16384 + 6144);   \
  } while (0)

#define ISS_B(DST, UB, NH) do {                       \
    DSR(DST[0], aB[UB][0], (NH) * (BN * 64) + 0);     \
    DSR(DST[1], aB[UB][1], (NH) * (BN * 64) + 0);     \
    if constexpr (NFQ == 2) {                         \
      DSR(DST[2], aB[UB][0], (NH) * (BN * 64) + 2048);\
      DSR(DST[3], aB[UB][1], (NH) * (BN * 64) + 2048);\
    }                                                 \
  } while (0)

#define MMX(MH, NH, AF, BF) do {                                                          \
    __builtin_amdgcn_s_setprio(1);                                                        \
    _Pragma("unroll")                                                                     \
    for (int m = 0; m < 4; ++m) {                                                         \
      acc[MH][NH][m][0] = __builtin_amdgcn_mfma_f32_16x16x32_f16(AF[m], BF[0], acc[MH][NH][m][0], 0, 0, 0);     \
      acc[MH][NH][m][0] = __builtin_amdgcn_mfma_f32_16x16x32_f16(AF[4 + m], BF[1], acc[MH][NH][m][0], 0, 0, 0); \
      if constexpr (NFQ == 2) {                                                           \
        acc[MH][NH][m][1] = __builtin_amdgcn_mfma_f32_16x16x32_f16(AF[m], BF[2], acc[MH][NH][m][1], 0, 0, 0);     \
        acc[MH][NH][m][1] = __builtin_amdgcn_mfma_f32_16x16x32_f16(AF[4 + m], BF[3], acc[MH][NH][m][1], 0, 0, 0); \
      }                                                                                   \
    }                                                                                     \
    __builtin_amdgcn_s_setprio(0);                                                        \
  } while (0)

  if constexpr (!PIPE) {
    // ================= serialized schedule (R6) =================
    stgA(0, 0, 0); stgA(0, 1, 0); stgB(0, 0, 0); stgB(0, 1, 0);
    stgA(1, 0, 1);
    VMC(0); BAR();

#pragma unroll 1
    for (int I = 0; I < NI; ++I) {
      const int v = 2 * I + 1, u2 = 2 * I + 2, v2 = 2 * I + 3;
      const bool st = (I + 1 < NI);
      f16x8 af[8], bf[4];
      // ---- UB0 (tile u = 2I)
      ISS_A(af, 0, 0); ISS_B(bf, 0, 0); stgA(1, 1, v);
      BAR(); WAITL(0); MMX(0, 0, af, bf); BAR();
      ISS_B(bf, 0, 1); stgB(1, 0, v); stgB(1, 1, v);
      BAR(); WAITL(0); MMX(0, 1, af, bf); BAR();
      ISS_A(af, 0, 1); if (st) stgA(0, 0, u2);
      BAR(); WAITL(0); MMX(1, 1, af, bf); BAR();
      ISS_B(bf, 0, 0); if (st) stgA(0, 1, u2);
      BAR(); WAITL(0); MMX(1, 0, af, bf);
      if (st) { VMC(4); } else { VMC(0); }
      BAR();
      // ---- UB1 (tile v = 2I+1)
      ISS_A(af, 1, 0); ISS_B(bf, 1, 0); if (st) stgB(0, 1, u2);
      BAR(); WAITL(0); MMX(0, 0, af, bf); BAR();
      ISS_B(bf, 1, 1); if (st) stgB(0, 0, u2);
      BAR(); WAITL(0); MMX(0, 1, af, bf); BAR();
      ISS_A(af, 1, 1); if (st) stgA(1, 0, v2);
      BAR(); WAITL(0); MMX(1, 1, af, bf); BAR();
      ISS_B(bf, 1, 0);
      BAR(); WAITL(0); MMX(1, 0, af, bf);
      if (st) { VMC(2); }
      BAR();
    }
  } else {
    // ============ pipelined schedule (cross-phase reads, counted lgkm) ========
    f16x8 afX[8], afY[8], bfP[4], bfQ[4];
    stgA(0, 0, 0); stgA(0, 1, 0); stgB(0, 0, 0); stgB(0, 1, 0);
    stgA(1, 0, 1); stgA(1, 1, 1); stgB(1, 0, 1); stgB(1, 1, 1);
    VMC(VPR); BAR();
    ISS_A(afX, 0, 0); ISS_B(bfP, 0, 0);

#pragma unroll 1
    for (int I = 0; I < NI; ++I) {
      const int u2 = 2 * I + 2, v2 = 2 * I + 3;
      const bool st = (I + 1 < NI);
      // p1
      ISS_B(bfQ, 0, 1);
      WAITL(NB); MMX(0, 0, afX, bfP); BAR();
      // p2
      ISS_A(afY, 0, 1);
      if (st) stgA(0, 0, u2);                       // a
      WAITL(8); MMX(0, 1, afX, bfQ); BAR();
      // p3
      ISS_B(bfP, 0, 0);
      if (st) stgB(0, 1, u2);                       // b
      WAITL(NB); MMX(1, 1, afY, bfQ);
      if (st) { VMC(VP3); } else { VMC(0); }
      BAR();
      // p4
      ISS_A(afX, 1, 0); ISS_B(bfQ, 1, 0);           // bfQ held through p8
      if (st) stgA(0, 1, u2);                       // c
      WAITL(8 + NB); MMX(1, 0, afY, bfP); BAR();
      // p5
      ISS_B(bfP, 1, 1);
      if (st) stgB(0, 0, u2);                       // d
      WAITL(NB); MMX(0, 0, afX, bfQ); BAR();
      // p6
      ISS_A(afY, 1, 1);
      if (st) { stgA(1, 0, v2); stgB(1, 0, v2); }   // e
      WAITL(8); MMX(0, 1, afX, bfP); BAR();
      // p7
      if (st) stgB(1, 1, v2);                       // f
      WAITL(0); MMX(1, 1, afY, bfP);
      if (st) { VMC(VP7); }
      BAR();
      // p8
      if (st) {
        ISS_A(afX, 0, 0); ISS_B(bfP, 0, 0);         // next iter p1's reads
        stgA(1, 1, v2);                             // g
        WAITL(8 + NB);
      } else {
        WAITL(0);
      }
      MMX(1, 0, afY, bfQ); BAR();
    }
  }
#undef ISS_A
#undef ISS_B
#undef MMX

  float scl = factor;
  if (scale_ptr != nullptr) scl = factor * scale_ptr[0];
  float* Cb = C + (size_t)bz * S_ * NN;
  const int r0 = bx * 256 + wm * 64 + kq * 4;
  const int c0 = by * BN + wn * (BN / 8) + fr;
#pragma unroll
  for (int mh = 0; mh < 2; ++mh)
#pragma unroll
    for (int nh = 0; nh < 2; ++nh)
#pragma unroll
      for (int m = 0; m < 4; ++m)
#pragma unroll
        for (int n = 0; n < NFQ; ++n)
#pragma unroll
          for (int r = 0; r < 4; ++r)
            Cb[(size_t)(r0 + mh * 128 + m * 16 + r) * NN + c0 + nh * (BN / 2) + n * 16] =
                acc[mh][nh][m][n][r] * scl;
}

// ---------------------------------------------------------------------------
// reductions
// ---------------------------------------------------------------------------
__device__ __forceinline__ float block_reduce_max(float v, float* red, int tid) {
#pragma unroll
  for (int o = 32; o > 0; o >>= 1) v = fmaxf(v, __shfl_xor(v, o, 64));
  __syncthreads();
  if ((tid & 63) == 0) red[tid >> 6] = v;
  __syncthreads();
  return fmaxf(fmaxf(red[0], red[1]), fmaxf(red[2], red[3]));
}
__device__ __forceinline__ float block_reduce_sum(float v, float* red, int tid) {
#pragma unroll
  for (int o = 32; o > 0; o >>= 1) v += __shfl_xor(v, o, 64);
  __syncthreads();
  if ((tid & 63) == 0) red[4 + (tid >> 6)] = v;
  __syncthreads();
  return (red[4] + red[5]) + (red[6] + red[7]);
}

// ---------------------------------------------------------------------------
// K2: row softmax, pad rows folded in (R7, proven).
// Valid rows: masked softmax -> fp16 P.
// Pad rows: fl(s-1e9) quantizes scores to a 64-wide grid; softmax = uniform
// 1/cnt over the top bucket -> write P = match ? fp16(1/cnt) : 0 and let the
// PV GEMM compute the mean. Boundary entries get an exact double recompute.
// ---------------------------------------------------------------------------
__global__ __launch_bounds__(256) void softmax_rows(const float* __restrict__ scores,
                                                    const int* __restrict__ mask,
                                                    const float* __restrict__ qg,
                                                    const float* __restrict__ kg,
                                                    const float* __restrict__ scale_ptr,
                                                    f16* __restrict__ P, int b0) {
  __shared__ float red[8];
  const int q = blockIdx.x, bl = blockIdx.y, bg = b0 + bl;
  const int tid = threadIdx.x;
  const float* srow = scores + ((size_t)bl * S_ + q) * S_;
  f16* prow = P + ((size_t)bl * S_ + q) * S_;
  const int j0 = tid * 8;
  float4 s0v = *(const float4*)(srow + j0);
  float4 s1v = *(const float4*)(srow + j0 + 4);
  float sv[8] = {s0v.x, s0v.y, s0v.z, s0v.w, s1v.x, s1v.y, s1v.z, s1v.w};

  if (mask[bg * S_ + q] == 0) {
    float vv[8];
    float lm = -3.4e38f;
#pragma unroll
    for (int i = 0; i < 8; ++i) {
      vv[i] = sv[i] - NEGC;
      lm = fmaxf(lm, vv[i]);
    }
    float g0 = block_reduce_max(lm, red, tid);
    float lm2 = -3.4e38f;
#pragma unroll 1
    for (int i = 0; i < 8; ++i) {
      float s = sv[i];
      float t = s * (1.0f / 64.0f);
      float rn = rintf(t);
      float dist = (0.5f - fabsf(t - rn)) * 64.0f;
      float v = vv[i];
      if (dist < 1e-3f && v >= g0 - 64.5f) {
        const float* qr = qg + ((size_t)bg * S_ + q) * D_;
        const float* kr = kg + ((size_t)bg * S_ + j0 + i) * D_;
        double acc = 0.0;
        for (int t2 = 0; t2 < D_; ++t2) acc += (double)qr[t2] * (double)kr[t2];
        v = (float)acc * scale_ptr[0] - NEGC;
      }
      vv[i] = v;
      lm2 = fmaxf(lm2, v);
    }
    float gf = block_reduce_max(lm2, red, tid);
    float local = 0.0f;
#pragma unroll
    for (int i = 0; i < 8; ++i) local += (vv[i] == gf) ? 1.0f : 0.0f;
    float cnt = block_reduce_sum(local, red, tid);
    f16 inv = (f16)(1.0f / cnt);
    union { f16 h[8]; uint4 u; } ow;
#pragma unroll
    for (int i = 0; i < 8; ++i) ow.h[i] = (vv[i] == gf) ? inv : (f16)0.0f;
    *(uint4*)(prow + j0) = ow.u;
    return;
  }

  int4 m0 = *(const int4*)(mask + (size_t)bg * S_ + j0);
  int4 m1 = *(const int4*)(mask + (size_t)bg * S_ + j0 + 4);
  int mk[8] = {m0.x, m0.y, m0.z, m0.w, m1.x, m1.y, m1.z, m1.w};
  int fl[8];
  float lm = -3.4e38f;
#pragma unroll
  for (int i = 0; i < 8; ++i) {
    fl[i] = (j0 + i <= q) && (mk[i] != 0);
    if (fl[i]) lm = fmaxf(lm, sv[i]);
  }
  float m = block_reduce_max(lm, red, tid);
  float ls = 0.0f;
#pragma unroll
  for (int i = 0; i < 8; ++i) {
    float e = fl[i] ? expf(sv[i] - m) : 0.0f;
    sv[i] = e; ls += e;
  }
  float sum = block_reduce_sum(ls, red, tid);
  float inv = 1.0f / sum;
  union { f16 h[8]; uint4 u; } ow;
#pragma unroll
  for (int i = 0; i < 8; ++i) ow.h[i] = (f16)(sv[i] * inv);
  *(uint4*)(prow + j0) = ow.u;
}

// ---------------------------------------------------------------------------
extern "C" void kernel_launch(void* const* d_in, const int* in_sizes, int n_in,
                              void* d_out, int out_size, void* d_ws, size_t ws_size,
                              hipStream_t stream) {
  (void)in_sizes; (void)n_in; (void)out_size;
  const float* q = (const float*)d_in[0];
  const float* k = (const float*)d_in[1];
  const int* mask = (const int*)d_in[2];
  const float* scale = (const float*)d_in[3];
  float* out = (float*)d_out;

  const size_t per_qx = (size_t)S_ * KEXP * 2;     // 12.58 MB
  const size_t per_khT = (size_t)D_ * S_ * 2;      //  4.19 MB
  const size_t per_sc = (size_t)S_ * S_ * 4;       // 16.78 MB
  const size_t per_batch = 2 * per_qx + per_khT + per_sc;  // P overlays qx

  int nb = (int)(ws_size / per_batch);
  if (nb > 4) nb = 4;   // 64*nb GEMM blocks: nb=4 -> 256 = exactly 1/CU
  if (nb < 1) nb = 1;

  char* w = (char*)d_ws;
  f16* qx = (f16*)w;
  f16* kx = (f16*)(w + (size_t)nb * per_qx);
  f16* khT = (f16*)(w + (size_t)nb * per_qx * 2);
  float* sc = (float*)(w + (size_t)nb * (per_qx * 2 + per_khT));
  f16* P = qx;                                     // overlay (qx dead post-QK^T)

  for (int b0 = 0; b0 < B_; b0 += nb) {
    int cb = (B_ - b0 < nb) ? (B_ - b0) : nb;
    const float* qb = q + (size_t)b0 * S_ * D_;
    const float* kb = k + (size_t)b0 * S_ * D_;

    int blocks0 = cb * ((S_ * D_ / 8) / 256);  // cb * 1024
    split_expand2<<<dim3(blocks0, 2), dim3(256), 0, stream>>>(qb, kb, qx, kx);
    transpose_cast<<<dim3(S_ / 64, D_ / 64, cb), dim3(256), 0, stream>>>(kb, khT);

    // scores = (q.k) * scale : factor 2^-12 undoes the 64x prescale on q,k
    gemm8p<KEXP, S_, 256, 1><<<dim3(64, cb), dim3(512), 0, stream>>>(
        qx, kx, sc, scale, 0.000244140625f);

    softmax_rows<<<dim3(S_, cb), dim3(256), 0, stream>>>(sc, mask, q, k, scale, P, b0);

    gemm8p<S_, D_, 128, 1><<<dim3(64, cb), dim3(512), 0, stream>>>(
        P, khT, out + (size_t)b0 * S_ * D_, nullptr, 1.0f);
  }
}

// Round 11
// 963.259 us; speedup vs baseline: 1.0196x; 1.0196x over previous
//
#include <hip/hip_runtime.h>
#include <hip/hip_bf16.h>
#include <stdint.h>

#define S_ 2048
#define D_ 1024
#define B_ 8
#define KEXP 3072            // 3 * D : [h,l,h] x [h,h,l] fp16 expansion
#define NEGC 1e9f

typedef _Float16 f16;
typedef _Float16 f16x8 __attribute__((ext_vector_type(8)));
typedef float f32x4 __attribute__((ext_vector_type(4)));

#define DSR(dst, addr, off) \
  asm volatile("ds_read_b128 %0, %1 offset:%c2" : "=v"(dst) : "v"(addr), "i"(off))
#define WAITL(n) do { asm volatile("s_waitcnt lgkmcnt(%c0)" :: "i"(n) : "memory"); \
                      __builtin_amdgcn_sched_barrier(0); } while (0)
#define VMC(n) asm volatile("s_waitcnt vmcnt(%c0)" :: "i"(n) : "memory")
#define BAR() __builtin_amdgcn_s_barrier()

// ---------------------------------------------------------------------------
// K0: split fp32 -> fp16 hi/lo 3-term expansion, input pre-scaled by 64.
// ---------------------------------------------------------------------------
__global__ __launch_bounds__(256) void split_expand2(const float* __restrict__ qin,
                                                     const float* __restrict__ kin,
                                                     f16* __restrict__ qx,
                                                     f16* __restrict__ kx) {
  const int isB = blockIdx.y;
  const float* in = isB ? kin : qin;
  f16* out = isB ? kx : qx;
  size_t idx = (size_t)blockIdx.x * 256 + threadIdx.x;
  const float4* ip = (const float4*)(in + idx * 8);
  float4 a = ip[0], b = ip[1];
  float vv[8] = {a.x, a.y, a.z, a.w, b.x, b.y, b.z, b.w};
  union { f16 h[24]; uint4 u[3]; } o;
#pragma unroll
  for (int t = 0; t < 8; ++t) {
    float v = vv[t] * 64.0f;
    f16 h = (f16)v;
    float r = v - (float)h;      // exact (Sterbenz)
    f16 l = (f16)r;
    o.h[3 * t + 0] = h;
    o.h[3 * t + 1] = isB ? h : l;
    o.h[3 * t + 2] = isB ? l : h;
  }
  uint4* op = (uint4*)(out + idx * 24);
  op[0] = o.u[0]; op[1] = o.u[1]; op[2] = o.u[2];
}

// ---------------------------------------------------------------------------
// K0c: khT[b][d][j] = fp16(k[b][j][d])
// ---------------------------------------------------------------------------
__global__ __launch_bounds__(256) void transpose_cast(const float* __restrict__ k,
                                                      f16* __restrict__ khT) {
  __shared__ f16 tile[64][65];
  int j0 = blockIdx.x * 64, d0 = blockIdx.y * 64;
  size_t bz = blockIdx.z;
  const float* kb = k + bz * (size_t)S_ * D_;
  f16* ob = khT + bz * (size_t)D_ * S_;
#pragma unroll
  for (int i = 0; i < 16; ++i) {
    int e = threadIdx.x + i * 256;
    int r = e >> 6, c = e & 63;
    tile[c][r] = (f16)kb[(size_t)(j0 + r) * D_ + d0 + c];
  }
  __syncthreads();
#pragma unroll
  for (int i = 0; i < 16; ++i) {
    int e = threadIdx.x + i * 256;
    int r = e >> 6, c = e & 63;
    ob[(size_t)(d0 + r) * S_ + j0 + c] = tile[r][c];
  }
}

// ---------------------------------------------------------------------------
// gemm4w: 256x256 tile, BK=64, FOUR waves (2x2), each wave owns 128x128.
// R10 bug: AS/BS were declared 256*32 f16 (16KB) while all address math
// assumed 32KB/buffer -> staging overran into BS (absmax 7.78). Fixed:
// 256*64 f16 = 32KB/buffer, 128KB LDS total (matches every offset).
// 256-thread block => 1 wave/SIMD => full 512-reg budget: acc 256 (AGPR) +
// frags ~96 + addr ~30 = ~386, no spill.
// Per K-tile, 4 phases (kc0,nh0)(kc0,nh1)(kc1,nh1)(kc1,nh0):
//  p1: issue ALL tile ds_reads in consumption order [bfP,afX,bfQ,afY](24),
//      stage A(t+1); WAITL(12) -> bfP,afX done; 32 MFMA.
//  p2: issue bfP<-(kc1,nh1); stage B(t+1); WAITL(12) -> bfQ done; 32 MFMA.
//  p3: issue bfQ<-(kc1,nh0); WAITL(4) -> afY,bfP done; 32 MFMA.
//  p4: WAITL(0); 32 MFMA; VMC(0); BAR.   (one barrier per tile)
// k-order monotone -> bit-identical (absmax must stay exactly 0.03125).
// ---------------------------------------------------------------------------
template <int KA, int NN>
__global__ __launch_bounds__(256, 1) void gemm4w(const f16* __restrict__ A,
                                                 const f16* __restrict__ Bm,
                                                 float* __restrict__ C,
                                                 const float* scale_ptr, float factor) {
  constexpr int NT = KA / 64;       // K-tiles
  __shared__ f16 AS[2][256 * 64];   // 2 x 32KB (256 rows x 64 k x 2B)
  __shared__ f16 BS[2][256 * 64];   // 2 x 32KB

  const int tid = threadIdx.x;
  const int lane = tid & 63, wave = tid >> 6;
  const int wm = wave >> 1, wn = wave & 1;        // 2 x 2 wave grid
  const int fr = lane & 15, kq = lane >> 4;

  // XCD-chunk swizzle (bijective: grid multiple of 8)
  int lin = blockIdx.x + gridDim.x * blockIdx.y;
  int ntot = gridDim.x * gridDim.y;
  int nid = (lin & 7) * (ntot >> 3) + (lin >> 3);
  int bz = nid >> 6, rem = nid & 63;
  int bx = rem & 7, by = rem >> 3;

  const f16* Ab = A + (size_t)bz * S_ * KA + (size_t)bx * 256 * KA;
  const f16* Bb = Bm + (size_t)bz * NN * KA + (size_t)by * 256 * KA;

  // fragment read bases; XOR swizzle on 16B chunks within 128B rows
  const int T0 = fr * 128 + (((0 + kq) ^ (fr & 7)) << 4);
  const int T1 = fr * 128 + (((4 + kq) ^ (fr & 7)) << 4);
  uint32_t asbase = (uint32_t)(uintptr_t)(__attribute__((address_space(3))) f16*)&AS[0][0];
  uint32_t bsbase = (uint32_t)(uintptr_t)(__attribute__((address_space(3))) f16*)&BS[0][0];
  uint32_t aA[2][2], aB[2][2];
#pragma unroll
  for (int b = 0; b < 2; ++b) {
    aA[b][0] = asbase + b * 32768 + wm * 16384 + T0;   // kc0
    aA[b][1] = asbase + b * 32768 + wm * 16384 + T1;   // kc1
    aB[b][0] = bsbase + b * 32768 + wn * 16384 + T0;
    aB[b][1] = bsbase + b * 32768 + wn * 16384 + T1;
  }

  // staging: linear LDS dest, inverse-swizzled global source
  const int srl = tid >> 3;                                             // 0..31
  const int sgc = ((((tid * 16) & 127) ^ (((tid >> 3) & 7) << 4)) >> 1);

  auto stgA = [&](int buf, int kt) {
#pragma unroll
    for (int i = 0; i < 8; ++i) {
      const f16* src = Ab + (size_t)(i * 32 + srl) * KA + kt * 64 + sgc;
      __builtin_amdgcn_global_load_lds(
          (const __attribute__((address_space(1))) void*)src,
          (__attribute__((address_space(3))) void*)&AS[buf][i * 2048 + wave * 512],
          16, 0, 0);
    }
  };
  auto stgB = [&](int buf, int kt) {
#pragma unroll
    for (int i = 0; i < 8; ++i) {
      const f16* src = Bb + (size_t)(i * 32 + srl) * KA + kt * 64 + sgc;
      __builtin_amdgcn_global_load_lds(
          (const __attribute__((address_space(1))) void*)src,
          (__attribute__((address_space(3))) void*)&BS[buf][i * 2048 + wave * 512],
          16, 0, 0);
    }
  };

  f32x4 acc[8][2][4];   // [m-frag][nh][n-frag] -> 256 f32
#pragma unroll
  for (int m = 0; m < 8; ++m)
#pragma unroll
    for (int h = 0; h < 2; ++h)
#pragma unroll
      for (int n = 0; n < 4; ++n)
#pragma unroll
        for (int r = 0; r < 4; ++r) acc[m][h][n][r] = 0.0f;

#define ISS_A4(DST, UB, KC) do {                    \
    DSR(DST[0], aA[UB][KC], 0);                     \
    DSR(DST[1], aA[UB][KC], 2048);                  \
    DSR(DST[2], aA[UB][KC], 4096);                  \
    DSR(DST[3], aA[UB][KC], 6144);                  \
    DSR(DST[4], aA[UB][KC], 8192);                  \
    DSR(DST[5], aA[UB][KC], 10240);                 \
    DSR(DST[6], aA[UB][KC], 12288);                 \
    DSR(DST[7], aA[UB][KC], 14336);                 \
  } while (0)

#define ISS_B4(DST, UB, KC, NH) do {                \
    DSR(DST[0], aB[UB][KC], (NH)*8192 + 0);         \
    DSR(DST[1], aB[UB][KC], (NH)*8192 + 2048);      \
    DSR(DST[2], aB[UB][KC], (NH)*8192 + 4096);      \
    DSR(DST[3], aB[UB][KC], (NH)*8192 + 6144);      \
  } while (0)

#define MM4(NH, AF, BF) do {                                                              \
    _Pragma("unroll")                                                                     \
    for (int m = 0; m < 8; ++m)                                                           \
      _Pragma("unroll")                                                                   \
      for (int n = 0; n < 4; ++n)                                                         \
        acc[m][NH][n] = __builtin_amdgcn_mfma_f32_16x16x32_f16(AF[m], BF[n], acc[m][NH][n], 0, 0, 0); \
  } while (0)

  // prologue: stage tile0 into buf0, publish
  stgA(0, 0); stgB(0, 0);
  VMC(0); BAR();

#pragma unroll 1
  for (int t = 0; t < NT; ++t) {
    const int b = t & 1;
    const bool st = (t + 1 < NT);
    f16x8 afX[8], afY[8], bfP[4], bfQ[4];
    // p1: all tile reads, consumption order
    ISS_B4(bfP, b, 0, 0);
    ISS_A4(afX, b, 0);
    ISS_B4(bfQ, b, 0, 1);
    ISS_A4(afY, b, 1);
    if (st) stgA(b ^ 1, t + 1);
    WAITL(12);
    MM4(0, afX, bfP);
    // p2
    ISS_B4(bfP, b, 1, 1);
    if (st) stgB(b ^ 1, t + 1);
    WAITL(12);
    MM4(1, afX, bfQ);
    // p3
    ISS_B4(bfQ, b, 1, 0);
    WAITL(4);
    MM4(1, afY, bfP);
    // p4
    WAITL(0);
    MM4(0, afY, bfQ);
    VMC(0);
    BAR();
  }
#undef ISS_A4
#undef ISS_B4
#undef MM4

  float scl = factor;
  if (scale_ptr != nullptr) scl = factor * scale_ptr[0];
  float* Cb = C + (size_t)bz * S_ * NN;
  const int r0 = bx * 256 + wm * 128 + kq * 4;
  const int c0 = by * 256 + wn * 128 + fr;
#pragma unroll
  for (int m = 0; m < 8; ++m)
#pragma unroll
    for (int h = 0; h < 2; ++h)
#pragma unroll
      for (int n = 0; n < 4; ++n)
#pragma unroll
        for (int r = 0; r < 4; ++r)
          Cb[(size_t)(r0 + m * 16 + r) * NN + c0 + h * 64 + n * 16] = acc[m][h][n][r] * scl;
}

// ---------------------------------------------------------------------------
// gemm8p PIPE=1, BN=128 (R8-proven PV GEMM) — unchanged.
// ---------------------------------------------------------------------------
template <int KA, int NN, int BN>
__global__ __launch_bounds__(512, 1) void gemm8p(const f16* __restrict__ A,
                                                 const f16* __restrict__ Bm,
                                                 float* __restrict__ C,
                                                 const float* scale_ptr,
                                                 float factor) {
  constexpr int NFQ = BN / 128;
  constexpr int GB = NFQ;
  constexpr int NB = 2 * NFQ;
  constexpr int VP3 = 2 + GB;
  constexpr int VP7 = 2 + 2 * GB;
  constexpr int VPR = 4 + 2 * GB;
  constexpr int NI = KA / 128;
  __shared__ f16 AS[2][256 * 64];
  __shared__ f16 BS[2][BN * 64];

  const int tid = threadIdx.x;
  const int lane = tid & 63, wave = tid >> 6;
  const int wm = wave >> 2, wn = wave & 3;
  const int fr = lane & 15, kq = lane >> 4;

  int lin = blockIdx.x + gridDim.x * blockIdx.y;
  int ntot = gridDim.x * gridDim.y;
  int nid = (lin & 7) * (ntot >> 3) + (lin >> 3);
  int bz = nid >> 6, rem = nid & 63;
  int bx = rem & 7, by = rem >> 3;

  const f16* Ab = A + (size_t)bz * S_ * KA + (size_t)bx * 256 * KA;
  const f16* Bb = Bm + (size_t)bz * NN * KA + (size_t)by * BN * KA;

  const int T0 = fr * 128 + (((0 + kq) ^ (fr & 7)) << 4);
  const int T1 = fr * 128 + (((4 + kq) ^ (fr & 7)) << 4);
  uint32_t asbase = (uint32_t)(uintptr_t)(__attribute__((address_space(3))) f16*)&AS[0][0];
  uint32_t bsbase = (uint32_t)(uintptr_t)(__attribute__((address_space(3))) f16*)&BS[0][0];
  uint32_t aA[2][2], aB[2][2];
#pragma unroll
  for (int b = 0; b < 2; ++b) {
    aA[b][0] = asbase + b * 32768 + wm * 8192 + T0;
    aA[b][1] = asbase + b * 32768 + wm * 8192 + T1;
    aB[b][0] = bsbase + b * (BN * 128) + wn * (BN * 16) + T0;
    aB[b][1] = bsbase + b * (BN * 128) + wn * (BN * 16) + T1;
  }

  const int srl = tid >> 3;
  const int sgc = ((((tid * 16) & 127) ^ (((tid >> 3) & 7) << 4)) >> 1);

  auto stgA = [&](int buf, int unit, int kt) {
#pragma unroll
    for (int i = 0; i < 2; ++i) {
      const f16* src = Ab + (size_t)(unit * 128 + i * 64 + srl) * KA + kt * 64 + sgc;
      __builtin_amdgcn_global_load_lds(
          (const __attribute__((address_space(1))) void*)src,
          (__attribute__((address_space(3))) void*)&AS[buf][unit * 8192 + i * 4096 + wave * 512],
          16, 0, 0);
    }
  };
  auto stgB = [&](int buf, int unit, int kt) {
#pragma unroll
    for (int i = 0; i < GB; ++i) {
      const f16* src = Bb + (size_t)(unit * (BN / 2) + i * 64 + srl) * KA + kt * 64 + sgc;
      __builtin_amdgcn_global_load_lds(
          (const __attribute__((address_space(1))) void*)src,
          (__attribute__((address_space(3))) void*)&BS[buf][unit * (BN * 32) + i * 4096 + wave * 512],
          16, 0, 0);
    }
  };

  f32x4 acc[2][2][4][2];
#pragma unroll
  for (int mh = 0; mh < 2; ++mh)
#pragma unroll
    for (int nh = 0; nh < 2; ++nh)
#pragma unroll
      for (int m = 0; m < 4; ++m)
#pragma unroll
        for (int n = 0; n < NFQ; ++n)
#pragma unroll
          for (int r = 0; r < 4; ++r) acc[mh][nh][m][n][r] = 0.0f;

#define ISS_A(DST, UB, MH) do {                  \
    DSR(DST[0], aA[UB][0], (MH)*16384 + 0);      \
    DSR(DST[1], aA[UB][0], (MH)*16384 + 2048);   \
    DSR(DST[2], aA[UB][0], (MH)*16384 + 4096);   \
    DSR(DST[3], aA[UB][0], (MH)*16384 + 6144);   \
    DSR(DST[4], aA[UB][1], (MH)*16384 + 0);      \
    DSR(DST[5], aA[UB][1], (MH)*16384 + 2048);   \
    DSR(DST[6], aA[UB][1], (MH)*16384 + 4096);   \
    DSR(DST[7], aA[UB][1], (MH)*16384 + 6144);   \
  } while (0)

#define ISS_B(DST, UB, NH) do {                       \
    DSR(DST[0], aB[UB][0], (NH) * (BN * 64) + 0);     \
    DSR(DST[1], aB[UB][1], (NH) * (BN * 64) + 0);     \
    if constexpr (NFQ == 2) {                         \
      DSR(DST[2], aB[UB][0], (NH) * (BN * 64) + 2048);\
      DSR(DST[3], aB[UB][1], (NH) * (BN * 64) + 2048);\
    }                                                 \
  } while (0)

#define MMX(MH, NH, AF, BF) do {                                                          \
    __builtin_amdgcn_s_setprio(1);                                                        \
    _Pragma("unroll")                                                                     \
    for (int m = 0; m < 4; ++m) {                                                         \
      acc[MH][NH][m][0] = __builtin_amdgcn_mfma_f32_16x16x32_f16(AF[m], BF[0], acc[MH][NH][m][0], 0, 0, 0);     \
      acc[MH][NH][m][0] = __builtin_amdgcn_mfma_f32_16x16x32_f16(AF[4 + m], BF[1], acc[MH][NH][m][0], 0, 0, 0); \
      if constexpr (NFQ == 2) {                                                           \
        acc[MH][NH][m][1] = __builtin_amdgcn_mfma_f32_16x16x32_f16(AF[m], BF[2], acc[MH][NH][m][1], 0, 0, 0);     \
        acc[MH][NH][m][1] = __builtin_amdgcn_mfma_f32_16x16x32_f16(AF[4 + m], BF[3], acc[MH][NH][m][1], 0, 0, 0); \
      }                                                                                   \
    }                                                                                     \
    __builtin_amdgcn_s_setprio(0);                                                        \
  } while (0)

  f16x8 afX[8], afY[8], bfP[4], bfQ[4];
  stgA(0, 0, 0); stgA(0, 1, 0); stgB(0, 0, 0); stgB(0, 1, 0);
  stgA(1, 0, 1); stgA(1, 1, 1); stgB(1, 0, 1); stgB(1, 1, 1);
  VMC(VPR); BAR();
  ISS_A(afX, 0, 0); ISS_B(bfP, 0, 0);

#pragma unroll 1
  for (int I = 0; I < NI; ++I) {
    const int u2 = 2 * I + 2, v2 = 2 * I + 3;
    const bool st = (I + 1 < NI);
    // p1
    ISS_B(bfQ, 0, 1);
    WAITL(NB); MMX(0, 0, afX, bfP); BAR();
    // p2
    ISS_A(afY, 0, 1);
    if (st) stgA(0, 0, u2);
    WAITL(8); MMX(0, 1, afX, bfQ); BAR();
    // p3
    ISS_B(bfP, 0, 0);
    if (st) stgB(0, 1, u2);
    WAITL(NB); MMX(1, 1, afY, bfQ);
    if (st) { VMC(VP3); } else { VMC(0); }
    BAR();
    // p4
    ISS_A(afX, 1, 0); ISS_B(bfQ, 1, 0);
    if (st) stgA(0, 1, u2);
    WAITL(8 + NB); MMX(1, 0, afY, bfP); BAR();
    // p5
    ISS_B(bfP, 1, 1);
    if (st) stgB(0, 0, u2);
    WAITL(NB); MMX(0, 0, afX, bfQ); BAR();
    // p6
    ISS_A(afY, 1, 1);
    if (st) { stgA(1, 0, v2); stgB(1, 0, v2); }
    WAITL(8); MMX(0, 1, afX, bfP); BAR();
    // p7
    if (st) stgB(1, 1, v2);
    WAITL(0); MMX(1, 1, afY, bfP);
    if (st) { VMC(VP7); }
    BAR();
    // p8
    if (st) {
      ISS_A(afX, 0, 0); ISS_B(bfP, 0, 0);
      stgA(1, 1, v2);
      WAITL(8 + NB);
    } else {
      WAITL(0);
    }
    MMX(1, 0, afY, bfQ); BAR();
  }
#undef ISS_A
#undef ISS_B
#undef MMX

  float scl = factor;
  if (scale_ptr != nullptr) scl = factor * scale_ptr[0];
  float* Cb = C + (size_t)bz * S_ * NN;
  const int r0 = bx * 256 + wm * 64 + kq * 4;
  const int c0 = by * BN + wn * (BN / 8) + fr;
#pragma unroll
  for (int mh = 0; mh < 2; ++mh)
#pragma unroll
    for (int nh = 0; nh < 2; ++nh)
#pragma unroll
      for (int m = 0; m < 4; ++m)
#pragma unroll
        for (int n = 0; n < NFQ; ++n)
#pragma unroll
          for (int r = 0; r < 4; ++r)
            Cb[(size_t)(r0 + mh * 128 + m * 16 + r) * NN + c0 + nh * (BN / 2) + n * 16] =
                acc[mh][nh][m][n][r] * scl;
}

// ---------------------------------------------------------------------------
// reductions
// ---------------------------------------------------------------------------
__device__ __forceinline__ float block_reduce_max(float v, float* red, int tid) {
#pragma unroll
  for (int o = 32; o > 0; o >>= 1) v = fmaxf(v, __shfl_xor(v, o, 64));
  __syncthreads();
  if ((tid & 63) == 0) red[tid >> 6] = v;
  __syncthreads();
  return fmaxf(fmaxf(red[0], red[1]), fmaxf(red[2], red[3]));
}
__device__ __forceinline__ float block_reduce_sum(float v, float* red, int tid) {
#pragma unroll
  for (int o = 32; o > 0; o >>= 1) v += __shfl_xor(v, o, 64);
  __syncthreads();
  if ((tid & 63) == 0) red[4 + (tid >> 6)] = v;
  __syncthreads();
  return (red[4] + red[5]) + (red[6] + red[7]);
}

// ---------------------------------------------------------------------------
// K2: row softmax, pad rows folded in (R7/R8-proven).
// ---------------------------------------------------------------------------
__global__ __launch_bounds__(256) void softmax_rows(const float* __restrict__ scores,
                                                    const int* __restrict__ mask,
                                                    const float* __restrict__ qg,
                                                    const float* __restrict__ kg,
                                                    const float* __restrict__ scale_ptr,
                                                    f16* __restrict__ P, int b0) {
  __shared__ float red[8];
  const int q = blockIdx.x, bl = blockIdx.y, bg = b0 + bl;
  const int tid = threadIdx.x;
  const float* srow = scores + ((size_t)bl * S_ + q) * S_;
  f16* prow = P + ((size_t)bl * S_ + q) * S_;
  const int j0 = tid * 8;
  float4 s0v = *(const float4*)(srow + j0);
  float4 s1v = *(const float4*)(srow + j0 + 4);
  float sv[8] = {s0v.x, s0v.y, s0v.z, s0v.w, s1v.x, s1v.y, s1v.z, s1v.w};

  if (mask[bg * S_ + q] == 0) {
    float vv[8];
    float lm = -3.4e38f;
#pragma unroll
    for (int i = 0; i < 8; ++i) {
      vv[i] = sv[i] - NEGC;
      lm = fmaxf(lm, vv[i]);
    }
    float g0 = block_reduce_max(lm, red, tid);
    float lm2 = -3.4e38f;
#pragma unroll 1
    for (int i = 0; i < 8; ++i) {
      float s = sv[i];
      float t = s * (1.0f / 64.0f);
      float rn = rintf(t);
      float dist = (0.5f - fabsf(t - rn)) * 64.0f;
      float v = vv[i];
      if (dist < 1e-3f && v >= g0 - 64.5f) {
        const float* qr = qg + ((size_t)bg * S_ + q) * D_;
        const float* kr = kg + ((size_t)bg * S_ + j0 + i) * D_;
        double acc = 0.0;
        for (int t2 = 0; t2 < D_; ++t2) acc += (double)qr[t2] * (double)kr[t2];
        v = (float)acc * scale_ptr[0] - NEGC;
      }
      vv[i] = v;
      lm2 = fmaxf(lm2, v);
    }
    float gf = block_reduce_max(lm2, red, tid);
    float local = 0.0f;
#pragma unroll
    for (int i = 0; i < 8; ++i) local += (vv[i] == gf) ? 1.0f : 0.0f;
    float cnt = block_reduce_sum(local, red, tid);
    f16 inv = (f16)(1.0f / cnt);
    union { f16 h[8]; uint4 u; } ow;
#pragma unroll
    for (int i = 0; i < 8; ++i) ow.h[i] = (vv[i] == gf) ? inv : (f16)0.0f;
    *(uint4*)(prow + j0) = ow.u;
    return;
  }

  int4 m0 = *(const int4*)(mask + (size_t)bg * S_ + j0);
  int4 m1 = *(const int4*)(mask + (size_t)bg * S_ + j0 + 4);
  int mk[8] = {m0.x, m0.y, m0.z, m0.w, m1.x, m1.y, m1.z, m1.w};
  int fl[8];
  float lm = -3.4e38f;
#pragma unroll
  for (int i = 0; i < 8; ++i) {
    fl[i] = (j0 + i <= q) && (mk[i] != 0);
    if (fl[i]) lm = fmaxf(lm, sv[i]);
  }
  float m = block_reduce_max(lm, red, tid);
  float ls = 0.0f;
#pragma unroll
  for (int i = 0; i < 8; ++i) {
    float e = fl[i] ? expf(sv[i] - m) : 0.0f;
    sv[i] = e; ls += e;
  }
  float sum = block_reduce_sum(ls, red, tid);
  float inv = 1.0f / sum;
  union { f16 h[8]; uint4 u; } ow;
#pragma unroll
  for (int i = 0; i < 8; ++i) ow.h[i] = (f16)(sv[i] * inv);
  *(uint4*)(prow + j0) = ow.u;
}

// ---------------------------------------------------------------------------
extern "C" void kernel_launch(void* const* d_in, const int* in_sizes, int n_in,
                              void* d_out, int out_size, void* d_ws, size_t ws_size,
                              hipStream_t stream) {
  (void)in_sizes; (void)n_in; (void)out_size;
  const float* q = (const float*)d_in[0];
  const float* k = (const float*)d_in[1];
  const int* mask = (const int*)d_in[2];
  const float* scale = (const float*)d_in[3];
  float* out = (float*)d_out;

  const size_t per_qx = (size_t)S_ * KEXP * 2;     // 12.58 MB
  const size_t per_khT = (size_t)D_ * S_ * 2;      //  4.19 MB
  const size_t per_sc = (size_t)S_ * S_ * 4;       // 16.78 MB
  const size_t per_batch = 2 * per_qx + per_khT + per_sc;  // P overlays qx

  int nb = (int)(ws_size / per_batch);
  if (nb > 4) nb = 4;   // 64*nb GEMM blocks: nb=4 -> 256 = exactly 1/CU
  if (nb < 1) nb = 1;

  char* w = (char*)d_ws;
  f16* qx = (f16*)w;
  f16* kx = (f16*)(w + (size_t)nb * per_qx);
  f16* khT = (f16*)(w + (size_t)nb * per_qx * 2);
  float* sc = (float*)(w + (size_t)nb * (per_qx * 2 + per_khT));
  f16* P = qx;                                     // overlay (qx dead post-QK^T)

  for (int b0 = 0; b0 < B_; b0 += nb) {
    int cb = (B_ - b0 < nb) ? (B_ - b0) : nb;
    const float* qb = q + (size_t)b0 * S_ * D_;
    const float* kb = k + (size_t)b0 * S_ * D_;

    int blocks0 = cb * ((S_ * D_ / 8) / 256);  // cb * 1024
    split_expand2<<<dim3(blocks0, 2), dim3(256), 0, stream>>>(qb, kb, qx, kx);
    transpose_cast<<<dim3(S_ / 64, D_ / 64, cb), dim3(256), 0, stream>>>(kb, khT);

    // scores = (q.k) * scale : factor 2^-12 undoes the 64x prescale on q,k
    gemm4w<KEXP, S_><<<dim3(64, cb), dim3(256), 0, stream>>>(
        qx, kx, sc, scale, 0.000244140625f);

    softmax_rows<<<dim3(S_, cb), dim3(256), 0, stream>>>(sc, mask, q, k, scale, P, b0);

    gemm8p<S_, D_, 128><<<dim3(64, cb), dim3(512), 0, stream>>>(
        P, khT, out + (size_t)b0 * S_ * D_, nullptr, 1.0f);
  }
}

// Round 12
// 427.340 us; speedup vs baseline: 2.2984x; 2.2541x over previous
//
#include <hip/hip_runtime.h>
#include <hip/hip_bf16.h>
#include <stdint.h>

#define S_ 2048
#define D_ 1024
#define B_ 8
#define KEXP 3072            // 3 * D : [h,l,h] x [h,h,l] fp16 expansion
#define NEGC 1e9f

typedef _Float16 f16;
typedef _Float16 f16x8 __attribute__((ext_vector_type(8)));
typedef float f32x4 __attribute__((ext_vector_type(4)));

#define DSR(dst, addr, off) \
  asm volatile("ds_read_b128 %0, %1 offset:%c2" : "=v"(dst) : "v"(addr), "i"(off))
#define WAITL(n) do { asm volatile("s_waitcnt lgkmcnt(%c0)" :: "i"(n) : "memory"); \
                      __builtin_amdgcn_sched_barrier(0); } while (0)
#define VMC(n) asm volatile("s_waitcnt vmcnt(%c0)" :: "i"(n) : "memory")
#define BAR() __builtin_amdgcn_s_barrier()

// ---------------------------------------------------------------------------
// K0: split fp32 -> fp16 hi/lo 3-term expansion, input pre-scaled by 64.
// pattern A (q): [h,l,h]   pattern B (k): [h,h,l];  blockIdx.y: 0=q, 1=k.
// ---------------------------------------------------------------------------
__global__ __launch_bounds__(256) void split_expand2(const float* __restrict__ qin,
                                                     const float* __restrict__ kin,
                                                     f16* __restrict__ qx,
                                                     f16* __restrict__ kx) {
  const int isB = blockIdx.y;
  const float* in = isB ? kin : qin;
  f16* out = isB ? kx : qx;
  size_t idx = (size_t)blockIdx.x * 256 + threadIdx.x;
  const float4* ip = (const float4*)(in + idx * 8);
  float4 a = ip[0], b = ip[1];
  float vv[8] = {a.x, a.y, a.z, a.w, b.x, b.y, b.z, b.w};
  union { f16 h[24]; uint4 u[3]; } o;
#pragma unroll
  for (int t = 0; t < 8; ++t) {
    float v = vv[t] * 64.0f;
    f16 h = (f16)v;
    float r = v - (float)h;      // exact (Sterbenz)
    f16 l = (f16)r;
    o.h[3 * t + 0] = h;
    o.h[3 * t + 1] = isB ? h : l;
    o.h[3 * t + 2] = isB ? l : h;
  }
  uint4* op = (uint4*)(out + idx * 24);
  op[0] = o.u[0]; op[1] = o.u[1]; op[2] = o.u[2];
}

// ---------------------------------------------------------------------------
// K0c: khT[b][d][j] = fp16(k[b][j][d])
// ---------------------------------------------------------------------------
__global__ __launch_bounds__(256) void transpose_cast(const float* __restrict__ k,
                                                      f16* __restrict__ khT) {
  __shared__ f16 tile[64][65];
  int j0 = blockIdx.x * 64, d0 = blockIdx.y * 64;
  size_t bz = blockIdx.z;
  const float* kb = k + bz * (size_t)S_ * D_;
  f16* ob = khT + bz * (size_t)D_ * S_;
#pragma unroll
  for (int i = 0; i < 16; ++i) {
    int e = threadIdx.x + i * 256;
    int r = e >> 6, c = e & 63;
    tile[c][r] = (f16)kb[(size_t)(j0 + r) * D_ + d0 + c];
  }
  __syncthreads();
#pragma unroll
  for (int i = 0; i < 16; ++i) {
    int e = threadIdx.x + i * 256;
    int r = e >> 6, c = e & 63;
    ob[(size_t)(d0 + r) * S_ + j0 + c] = tile[r][c];
  }
}

// ---------------------------------------------------------------------------
// 8-phase GEMM (B-transposed), snake-order fragment reuse; two schedules:
// PIPE=0 (QK^T, NFQ=2): per phase {ds_read issue -> lgkm(0) -> MFMA ->
//   [vmcnt] -> BAR}. SINGLE barrier per phase (R12): the closing barrier
//   follows each wave's lgkm0 (reads retired), so a stage issued in phase
//   p+1 can never overwrite a region still being read; VMC(4/2)+BAR are the
//   publication points (ledger identical to R6's proven one; the old
//   opening barrier protected nothing). launch_bounds(512,2), VGPR ~120.
// PIPE=1 (PV, NFQ=1): cross-phase read pipelining with counted lgkm,
//   launch_bounds(512,1); live set fits (R8-proven).
// Both: dbuf-2 LDS, per-element k-order identical -> bit-identical results
// (absmax must stay exactly 0.03125 — race canary).
// ---------------------------------------------------------------------------
template <int KA, int NN, int BN, int PIPE>
__global__ __launch_bounds__(512, PIPE ? 1 : 2) void gemm8p(const f16* __restrict__ A,
                                                            const f16* __restrict__ Bm,
                                                            float* __restrict__ C,
                                                            const float* scale_ptr,
                                                            float factor) {
  constexpr int NFQ = BN / 128;     // B frags per phase (2 or 1)
  constexpr int GB = NFQ;           // gloads per stgB
  constexpr int NB = 2 * NFQ;       // ds_reads per B-issue
  constexpr int VP3 = 2 + GB;       // vmcnt at p3-end (PIPE)
  constexpr int VP7 = 2 + 2 * GB;   // vmcnt at p7-end (PIPE)
  constexpr int VPR = 4 + 2 * GB;   // prologue vmcnt (PIPE)
  constexpr int NI = KA / 128;      // iterations (2 K-tiles each)
  __shared__ f16 AS[2][256 * 64];   // 2 x 32KB
  __shared__ f16 BS[2][BN * 64];    // 2 x (32|16)KB

  const int tid = threadIdx.x;
  const int lane = tid & 63, wave = tid >> 6;
  const int wm = wave >> 2, wn = wave & 3;        // 2 x 4 wave grid
  const int fr = lane & 15, kq = lane >> 4;

  // XCD-chunk swizzle (bijective: grid multiple of 8)
  int lin = blockIdx.x + gridDim.x * blockIdx.y;
  int ntot = gridDim.x * gridDim.y;
  int nid = (lin & 7) * (ntot >> 3) + (lin >> 3);
  int bz = nid >> 6, rem = nid & 63;
  int bx = rem & 7, by = rem >> 3;

  const f16* Ab = A + (size_t)bz * S_ * KA + (size_t)bx * 256 * KA;
  const f16* Bb = Bm + (size_t)bz * NN * KA + (size_t)by * BN * KA;

  // fragment read bases; XOR swizzle on 16B chunks (0 conflicts, R3-R11)
  const int T0 = fr * 128 + (((0 + kq) ^ (fr & 7)) << 4);
  const int T1 = fr * 128 + (((4 + kq) ^ (fr & 7)) << 4);
  uint32_t asbase = (uint32_t)(uintptr_t)(__attribute__((address_space(3))) f16*)&AS[0][0];
  uint32_t bsbase = (uint32_t)(uintptr_t)(__attribute__((address_space(3))) f16*)&BS[0][0];
  uint32_t aA[2][2], aB[2][2];
#pragma unroll
  for (int b = 0; b < 2; ++b) {
    aA[b][0] = asbase + b * 32768 + wm * 8192 + T0;
    aA[b][1] = asbase + b * 32768 + wm * 8192 + T1;
    aB[b][0] = bsbase + b * (BN * 128) + wn * (BN * 16) + T0;
    aB[b][1] = bsbase + b * (BN * 128) + wn * (BN * 16) + T1;
  }

  // staging: linear LDS dest, inverse-swizzled global source
  const int srl = tid >> 3;
  const int sgc = ((((tid * 16) & 127) ^ (((tid >> 3) & 7) << 4)) >> 1);

  auto stgA = [&](int buf, int unit, int kt) {
#pragma unroll
    for (int i = 0; i < 2; ++i) {
      const f16* src = Ab + (size_t)(unit * 128 + i * 64 + srl) * KA + kt * 64 + sgc;
      __builtin_amdgcn_global_load_lds(
          (const __attribute__((address_space(1))) void*)src,
          (__attribute__((address_space(3))) void*)&AS[buf][unit * 8192 + i * 4096 + wave * 512],
          16, 0, 0);
    }
  };
  auto stgB = [&](int buf, int unit, int kt) {
#pragma unroll
    for (int i = 0; i < GB; ++i) {
      const f16* src = Bb + (size_t)(unit * (BN / 2) + i * 64 + srl) * KA + kt * 64 + sgc;
      __builtin_amdgcn_global_load_lds(
          (const __attribute__((address_space(1))) void*)src,
          (__attribute__((address_space(3))) void*)&BS[buf][unit * (BN * 32) + i * 4096 + wave * 512],
          16, 0, 0);
    }
  };

  f32x4 acc[2][2][4][2];
#pragma unroll
  for (int mh = 0; mh < 2; ++mh)
#pragma unroll
    for (int nh = 0; nh < 2; ++nh)
#pragma unroll
      for (int m = 0; m < 4; ++m)
#pragma unroll
        for (int n = 0; n < NFQ; ++n)
#pragma unroll
          for (int r = 0; r < 4; ++r) acc[mh][nh][m][n][r] = 0.0f;

#define ISS_A(DST, UB, MH) do {                  \
    DSR(DST[0], aA[UB][0], (MH)*16384 + 0);      \
    DSR(DST[1], aA[UB][0], (MH)*16384 + 2048);   \
    DSR(DST[2], aA[UB][0], (MH)*16384 + 4096);   \
    DSR(DST[3], aA[UB][0], (MH)*16384 + 6144);   \
    DSR(DST[4], aA[UB][1], (MH)*16384 + 0);      \
    DSR(DST[5], aA[UB][1], (MH)*16384 + 2048);   \
    DSR(DST[6], aA[UB][1], (MH)*16384 + 4096);   \
    DSR(DST[7], aA[UB][1], (MH)*16384 + 6144);   \
  } while (0)

#define ISS_B(DST, UB, NH) do {                       \
    DSR(DST[0], aB[UB][0], (NH) * (BN * 64) + 0);     \
    DSR(DST[1], aB[UB][1], (NH) * (BN * 64) + 0);     \
    if constexpr (NFQ == 2) {                         \
      DSR(DST[2], aB[UB][0], (NH) * (BN * 64) + 2048);\
      DSR(DST[3], aB[UB][1], (NH) * (BN * 64) + 2048);\
    }                                                 \
  } while (0)

#define MMX(MH, NH, AF, BF) do {                                                          \
    __builtin_amdgcn_s_setprio(1);                                                        \
    _Pragma("unroll")                                                                     \
    for (int m = 0; m < 4; ++m) {                                                         \
      acc[MH][NH][m][0] = __builtin_amdgcn_mfma_f32_16x16x32_f16(AF[m], BF[0], acc[MH][NH][m][0], 0, 0, 0);     \
      acc[MH][NH][m][0] = __builtin_amdgcn_mfma_f32_16x16x32_f16(AF[4 + m], BF[1], acc[MH][NH][m][0], 0, 0, 0); \
      if constexpr (NFQ == 2) {                                                           \
        acc[MH][NH][m][1] = __builtin_amdgcn_mfma_f32_16x16x32_f16(AF[m], BF[2], acc[MH][NH][m][1], 0, 0, 0);     \
        acc[MH][NH][m][1] = __builtin_amdgcn_mfma_f32_16x16x32_f16(AF[4 + m], BF[3], acc[MH][NH][m][1], 0, 0, 0); \
      }                                                                                   \
    }                                                                                     \
    __builtin_amdgcn_s_setprio(0);                                                        \
  } while (0)

  if constexpr (!PIPE) {
    // ========== serialized snake, SINGLE barrier per phase (R12) ==========
    stgA(0, 0, 0); stgA(0, 1, 0); stgB(0, 0, 0); stgB(0, 1, 0);
    stgA(1, 0, 1);
    VMC(0); BAR();

#pragma unroll 1
    for (int I = 0; I < NI; ++I) {
      const int v = 2 * I + 1, u2 = 2 * I + 2, v2 = 2 * I + 3;
      const bool st = (I + 1 < NI);
      f16x8 af[8], bf[4];
      // ---- UB0 (tile u = 2I)
      ISS_A(af, 0, 0); ISS_B(bf, 0, 0); stgA(1, 1, v);
      WAITL(0); MMX(0, 0, af, bf); BAR();
      ISS_B(bf, 0, 1); stgB(1, 0, v); stgB(1, 1, v);
      WAITL(0); MMX(0, 1, af, bf); BAR();
      ISS_A(af, 0, 1); if (st) stgA(0, 0, u2);
      WAITL(0); MMX(1, 1, af, bf); BAR();
      ISS_B(bf, 0, 0); if (st) stgA(0, 1, u2);
      WAITL(0); MMX(1, 0, af, bf);
      if (st) { VMC(4); } else { VMC(0); }
      BAR();
      // ---- UB1 (tile v = 2I+1)
      ISS_A(af, 1, 0); ISS_B(bf, 1, 0); if (st) stgB(0, 1, u2);
      WAITL(0); MMX(0, 0, af, bf); BAR();
      ISS_B(bf, 1, 1); if (st) stgB(0, 0, u2);
      WAITL(0); MMX(0, 1, af, bf); BAR();
      ISS_A(af, 1, 1); if (st) stgA(1, 0, v2);
      WAITL(0); MMX(1, 1, af, bf); BAR();
      ISS_B(bf, 1, 0);
      WAITL(0); MMX(1, 0, af, bf);
      if (st) { VMC(2); }
      BAR();
    }
  } else {
    // ============ pipelined schedule (cross-phase reads, counted lgkm) ========
    f16x8 afX[8], afY[8], bfP[4], bfQ[4];
    stgA(0, 0, 0); stgA(0, 1, 0); stgB(0, 0, 0); stgB(0, 1, 0);
    stgA(1, 0, 1); stgA(1, 1, 1); stgB(1, 0, 1); stgB(1, 1, 1);
    VMC(VPR); BAR();
    ISS_A(afX, 0, 0); ISS_B(bfP, 0, 0);

#pragma unroll 1
    for (int I = 0; I < NI; ++I) {
      const int u2 = 2 * I + 2, v2 = 2 * I + 3;
      const bool st = (I + 1 < NI);
      // p1
      ISS_B(bfQ, 0, 1);
      WAITL(NB); MMX(0, 0, afX, bfP); BAR();
      // p2
      ISS_A(afY, 0, 1);
      if (st) stgA(0, 0, u2);
      WAITL(8); MMX(0, 1, afX, bfQ); BAR();
      // p3
      ISS_B(bfP, 0, 0);
      if (st) stgB(0, 1, u2);
      WAITL(NB); MMX(1, 1, afY, bfQ);
      if (st) { VMC(VP3); } else { VMC(0); }
      BAR();
      // p4
      ISS_A(afX, 1, 0); ISS_B(bfQ, 1, 0);
      if (st) stgA(0, 1, u2);
      WAITL(8 + NB); MMX(1, 0, afY, bfP); BAR();
      // p5
      ISS_B(bfP, 1, 1);
      if (st) stgB(0, 0, u2);
      WAITL(NB); MMX(0, 0, afX, bfQ); BAR();
      // p6
      ISS_A(afY, 1, 1);
      if (st) { stgA(1, 0, v2); stgB(1, 0, v2); }
      WAITL(8); MMX(0, 1, afX, bfP); BAR();
      // p7
      if (st) stgB(1, 1, v2);
      WAITL(0); MMX(1, 1, afY, bfP);
      if (st) { VMC(VP7); }
      BAR();
      // p8
      if (st) {
        ISS_A(afX, 0, 0); ISS_B(bfP, 0, 0);
        stgA(1, 1, v2);
        WAITL(8 + NB);
      } else {
        WAITL(0);
      }
      MMX(1, 0, afY, bfQ); BAR();
    }
  }
#undef ISS_A
#undef ISS_B
#undef MMX

  float scl = factor;
  if (scale_ptr != nullptr) scl = factor * scale_ptr[0];
  float* Cb = C + (size_t)bz * S_ * NN;
  const int r0 = bx * 256 + wm * 64 + kq * 4;
  const int c0 = by * BN + wn * (BN / 8) + fr;
#pragma unroll
  for (int mh = 0; mh < 2; ++mh)
#pragma unroll
    for (int nh = 0; nh < 2; ++nh)
#pragma unroll
      for (int m = 0; m < 4; ++m)
#pragma unroll
        for (int n = 0; n < NFQ; ++n)
#pragma unroll
          for (int r = 0; r < 4; ++r)
            Cb[(size_t)(r0 + mh * 128 + m * 16 + r) * NN + c0 + nh * (BN / 2) + n * 16] =
                acc[mh][nh][m][n][r] * scl;
}

// ---------------------------------------------------------------------------
// reductions
// ---------------------------------------------------------------------------
__device__ __forceinline__ float block_reduce_max(float v, float* red, int tid) {
#pragma unroll
  for (int o = 32; o > 0; o >>= 1) v = fmaxf(v, __shfl_xor(v, o, 64));
  __syncthreads();
  if ((tid & 63) == 0) red[tid >> 6] = v;
  __syncthreads();
  return fmaxf(fmaxf(red[0], red[1]), fmaxf(red[2], red[3]));
}
__device__ __forceinline__ float block_reduce_sum(float v, float* red, int tid) {
#pragma unroll
  for (int o = 32; o > 0; o >>= 1) v += __shfl_xor(v, o, 64);
  __syncthreads();
  if ((tid & 63) == 0) red[4 + (tid >> 6)] = v;
  __syncthreads();
  return (red[4] + red[5]) + (red[6] + red[7]);
}

// ---------------------------------------------------------------------------
// K2: row softmax, pad rows folded in (R7/R8-proven).
// ---------------------------------------------------------------------------
__global__ __launch_bounds__(256) void softmax_rows(const float* __restrict__ scores,
                                                    const int* __restrict__ mask,
                                                    const float* __restrict__ qg,
                                                    const float* __restrict__ kg,
                                                    const float* __restrict__ scale_ptr,
                                                    f16* __restrict__ P, int b0) {
  __shared__ float red[8];
  const int q = blockIdx.x, bl = blockIdx.y, bg = b0 + bl;
  const int tid = threadIdx.x;
  const float* srow = scores + ((size_t)bl * S_ + q) * S_;
  f16* prow = P + ((size_t)bl * S_ + q) * S_;
  const int j0 = tid * 8;
  float4 s0v = *(const float4*)(srow + j0);
  float4 s1v = *(const float4*)(srow + j0 + 4);
  float sv[8] = {s0v.x, s0v.y, s0v.z, s0v.w, s1v.x, s1v.y, s1v.z, s1v.w};

  if (mask[bg * S_ + q] == 0) {
    float vv[8];
    float lm = -3.4e38f;
#pragma unroll
    for (int i = 0; i < 8; ++i) {
      vv[i] = sv[i] - NEGC;
      lm = fmaxf(lm, vv[i]);
    }
    float g0 = block_reduce_max(lm, red, tid);
    float lm2 = -3.4e38f;
#pragma unroll 1
    for (int i = 0; i < 8; ++i) {
      float s = sv[i];
      float t = s * (1.0f / 64.0f);
      float rn = rintf(t);
      float dist = (0.5f - fabsf(t - rn)) * 64.0f;
      float v = vv[i];
      if (dist < 1e-3f && v >= g0 - 64.5f) {
        const float* qr = qg + ((size_t)bg * S_ + q) * D_;
        const float* kr = kg + ((size_t)bg * S_ + j0 + i) * D_;
        double acc = 0.0;
        for (int t2 = 0; t2 < D_; ++t2) acc += (double)qr[t2] * (double)kr[t2];
        v = (float)acc * scale_ptr[0] - NEGC;
      }
      vv[i] = v;
      lm2 = fmaxf(lm2, v);
    }
    float gf = block_reduce_max(lm2, red, tid);
    float local = 0.0f;
#pragma unroll
    for (int i = 0; i < 8; ++i) local += (vv[i] == gf) ? 1.0f : 0.0f;
    float cnt = block_reduce_sum(local, red, tid);
    f16 inv = (f16)(1.0f / cnt);
    union { f16 h[8]; uint4 u; } ow;
#pragma unroll
    for (int i = 0; i < 8; ++i) ow.h[i] = (vv[i] == gf) ? inv : (f16)0.0f;
    *(uint4*)(prow + j0) = ow.u;
    return;
  }

  int4 m0 = *(const int4*)(mask + (size_t)bg * S_ + j0);
  int4 m1 = *(const int4*)(mask + (size_t)bg * S_ + j0 + 4);
  int mk[8] = {m0.x, m0.y, m0.z, m0.w, m1.x, m1.y, m1.z, m1.w};
  int fl[8];
  float lm = -3.4e38f;
#pragma unroll
  for (int i = 0; i < 8; ++i) {
    fl[i] = (j0 + i <= q) && (mk[i] != 0);
    if (fl[i]) lm = fmaxf(lm, sv[i]);
  }
  float m = block_reduce_max(lm, red, tid);
  float ls = 0.0f;
#pragma unroll
  for (int i = 0; i < 8; ++i) {
    float e = fl[i] ? expf(sv[i] - m) : 0.0f;
    sv[i] = e; ls += e;
  }
  float sum = block_reduce_sum(ls, red, tid);
  float inv = 1.0f / sum;
  union { f16 h[8]; uint4 u; } ow;
#pragma unroll
  for (int i = 0; i < 8; ++i) ow.h[i] = (f16)(sv[i] * inv);
  *(uint4*)(prow + j0) = ow.u;
}

// ---------------------------------------------------------------------------
extern "C" void kernel_launch(void* const* d_in, const int* in_sizes, int n_in,
                              void* d_out, int out_size, void* d_ws, size_t ws_size,
                              hipStream_t stream) {
  (void)in_sizes; (void)n_in; (void)out_size;
  const float* q = (const float*)d_in[0];
  const float* k = (const float*)d_in[1];
  const int* mask = (const int*)d_in[2];
  const float* scale = (const float*)d_in[3];
  float* out = (float*)d_out;

  const size_t per_qx = (size_t)S_ * KEXP * 2;     // 12.58 MB
  const size_t per_khT = (size_t)D_ * S_ * 2;      //  4.19 MB
  const size_t per_sc = (size_t)S_ * S_ * 4;       // 16.78 MB
  const size_t per_batch = 2 * per_qx + per_khT + per_sc;  // P overlays qx

  int nb = (int)(ws_size / per_batch);
  if (nb > 4) nb = 4;   // 64*nb GEMM blocks: nb=4 -> 256 = exactly 1/CU
  if (nb < 1) nb = 1;

  char* w = (char*)d_ws;
  f16* qx = (f16*)w;
  f16* kx = (f16*)(w + (size_t)nb * per_qx);
  f16* khT = (f16*)(w + (size_t)nb * per_qx * 2);
  float* sc = (float*)(w + (size_t)nb * (per_qx * 2 + per_khT));
  f16* P = qx;                                     // overlay (qx dead post-QK^T)

  for (int b0 = 0; b0 < B_; b0 += nb) {
    int cb = (B_ - b0 < nb) ? (B_ - b0) : nb;
    const float* qb = q + (size_t)b0 * S_ * D_;
    const float* kb = k + (size_t)b0 * S_ * D_;

    int blocks0 = cb * ((S_ * D_ / 8) / 256);  // cb * 1024
    split_expand2<<<dim3(blocks0, 2), dim3(256), 0, stream>>>(qb, kb, qx, kx);
    transpose_cast<<<dim3(S_ / 64, D_ / 64, cb), dim3(256), 0, stream>>>(kb, khT);

    // scores = (q.k) * scale : factor 2^-12 undoes the 64x prescale on q,k
    gemm8p<KEXP, S_, 256, 0><<<dim3(64, cb), dim3(512), 0, stream>>>(
        qx, kx, sc, scale, 0.000244140625f);

    softmax_rows<<<dim3(S_, cb), dim3(256), 0, stream>>>(sc, mask, q, k, scale, P, b0);

    gemm8p<S_, D_, 128, 1><<<dim3(64, cb), dim3(512), 0, stream>>>(
        P, khT, out + (size_t)b0 * S_ * D_, nullptr, 1.0f);
  }
}